// Round 4
// baseline (1389.395 us; speedup 1.0000x reference)
//
#include <hip/hip_runtime.h>
#include <hip/hip_bf16.h>
#include <stdint.h>
#include <stddef.h>

typedef __bf16 bf16_t;
typedef __bf16 bf16x8 __attribute__((ext_vector_type(8)));
typedef __bf16 bf16x4 __attribute__((ext_vector_type(4)));
typedef float  f32x4  __attribute__((ext_vector_type(4)));

#define MFMA16(a, b, c) __builtin_amdgcn_mfma_f32_16x16x32_bf16((a), (b), (c), 0, 0, 0)

namespace cfg {
constexpr int B    = 131072;
constexpr int DIM  = 40;
constexpr int H    = 128;
constexpr int AD   = 20;
constexpr int L    = 6;
constexpr int MB   = 32;     // rows per block
constexpr int NTH  = 256;    // threads per block (4 waves)

// transposed-weight layout (bf16 element offsets)
constexpr int W1_TILE   = 128 * 40;          // per 32-wide K tile (N=128, padded k=40)
constexpr int W1S_LSTR  = 9 * W1_TILE;       // 46080 per layer (K padded 288 = 9 tiles)
constexpr int W2S_OFF   = 6 * W1S_LSTR;      // 276480
constexpr int W23_LSTR  = 4 * W1_TILE;       // 20480 per layer
constexpr int W3S_OFF   = W2S_OFF + 6 * W23_LSTR;  // 399360
constexpr int WST_OFF   = W3S_OFF + 6 * W23_LSTR;  // 522240
constexpr int WST_TILE  = 64 * 40;           // (N=64: [s(20)|pad|t(20)|pad], padded k=40)
constexpr int WST_LSTR  = 4 * WST_TILE;      // 10240 per layer
constexpr int WS_BF16_TOTAL = WST_OFF + 6 * WST_LSTR;  // 583680 elems
}

// Static module-scope staging; rewritten by prep_kernel every launch.
__device__ bf16_t g_wsb[cfg::WS_BF16_TOTAL];
__device__ int    g_gtab[240];

// ---------------------------------------------------------------------------
// Prep: fp32 weights -> bf16, transposed/padded [layer][kt][n][40] MFMA tiles,
// and gather tables ga[i][j] = perm[i][idx_a[i][j]] (likewise gb from idx_b).
// ---------------------------------------------------------------------------
__global__ void prep_kernel(const float* __restrict__ W1, const float* __restrict__ W2,
                            const float* __restrict__ W3, const float* __restrict__ Ws,
                            const float* __restrict__ Wt, const int* __restrict__ perm,
                            const int* __restrict__ ia, const int* __restrict__ ib)
{
    using namespace cfg;
    int t = blockIdx.x * blockDim.x + threadIdx.x;
    if (t < W2S_OFF) {
        // W1s: [6][9][128][40]; h0 k-layout: [z_a(20) pad12 | ctx(128) | t_e(128)]
        int i = t / W1S_LSTR, r = t % W1S_LSTR;
        int kt = r / W1_TILE, r2 = r % W1_TILE;
        int n = r2 / 40, kl = r2 % 40;
        int k = kt * 32 + kl;
        float v = 0.f;
        if (kl < 32) {
            if (k < 20)       v = W1[(i * 276 + k) * 128 + n];
            else if (k >= 32) v = W1[(i * 276 + (k - 12)) * 128 + n];
        }
        g_wsb[t] = (bf16_t)v;
    } else if (t < W3S_OFF) {
        int u = t - W2S_OFF;
        int i = u / W23_LSTR, r = u % W23_LSTR;
        int kt = r / W1_TILE, r2 = r % W1_TILE;
        int n = r2 / 40, kl = r2 % 40;
        int k = kt * 32 + kl;
        g_wsb[t] = (bf16_t)((kl < 32) ? W2[(i * 128 + k) * 128 + n] : 0.f);
    } else if (t < cfg::WST_OFF) {
        int u = t - W3S_OFF;
        int i = u / W23_LSTR, r = u % W23_LSTR;
        int kt = r / W1_TILE, r2 = r % W1_TILE;
        int n = r2 / 40, kl = r2 % 40;
        int k = kt * 32 + kl;
        g_wsb[t] = (bf16_t)((kl < 32) ? W3[(i * 128 + k) * 128 + n] : 0.f);
    } else if (t < WS_BF16_TOTAL) {
        int u = t - WST_OFF;
        int i = u / WST_LSTR, r = u % WST_LSTR;
        int kt = r / WST_TILE, r2 = r % WST_TILE;
        int n = r2 / 40, kl = r2 % 40;
        int k = kt * 32 + kl;
        float v = 0.f;
        if (kl < 32) {
            if (n < 20)                 v = Ws[(i * 128 + k) * 20 + n];
            else if (n >= 32 && n < 52) v = Wt[(i * 128 + k) * 20 + (n - 32)];
        }
        g_wsb[t] = (bf16_t)v;
    } else if (t < WS_BF16_TOTAL + 240) {
        int u = t - WS_BF16_TOTAL;
        if (u < 120) g_gtab[u] = perm[(u / 20) * 40 + ia[u]];
        else { int v2 = u - 120; g_gtab[u] = perm[(v2 / 20) * 40 + ib[v2]]; }
    }
}

// synchronous weight staging: global -> VGPR -> LDS, 16B per thread-step
__device__ __forceinline__ void stage_w(const bf16_t* g, bf16_t* l, int bytes, int tid)
{
    const char* gp = (const char*)g;
    char* lp = (char*)l;
    for (int off = tid * 16; off < bytes; off += cfg::NTH * 16)
        *(bf16x8*)(lp + off) = *(const bf16x8*)(gp + off);
}

// [32 x K] @ [K x 128] + bias -> SiLU -> hout[32][136].
// Single-buffered wbuf with leading+trailing barriers per K-tile: race-free.
__device__ __forceinline__ void mm_block(
    const bf16_t* hin, int istride, int nkt, const bf16_t* wsrc,
    const float* bias, bf16_t* hout, bf16_t* wbuf,
    int tid, int q, int c, int r0, int c0)
{
    using namespace cfg;
    f32x4 acc[4] = {};
    for (int kt = 0; kt < nkt; ++kt) {
        __syncthreads();   // previous wbuf readers (and hin producers on kt==0) done
        stage_w(wsrc + kt * W1_TILE, wbuf, W1_TILE * 2, tid);
        __syncthreads();   // wbuf ready
        bf16x8 af = *(const bf16x8*)&hin[(r0 + c) * istride + kt * 32 + q * 8];
        #pragma unroll
        for (int nt = 0; nt < 4; ++nt) {
            bf16x8 bfr = *(const bf16x8*)&wbuf[(c0 + nt * 16 + c) * 40 + q * 8];
            acc[nt] = MFMA16(af, bfr, acc[nt]);
        }
    }
    #pragma unroll
    for (int nt = 0; nt < 4; ++nt) {
        int col = c0 + nt * 16 + c;
        float bv = bias[col];
        #pragma unroll
        for (int rr = 0; rr < 4; ++rr) {
            float v = acc[nt][rr] + bv;
            v = v / (1.f + __expf(-v));
            hout[(r0 + q * 4 + rr) * 136 + col] = (bf16_t)v;
        }
    }
}

__global__ __launch_bounds__(256, 2) void flow_main(
    const float* __restrict__ x, const float* __restrict__ ctx, const float* __restrict__ te,
    const float* __restrict__ b1, const float* __restrict__ b2, const float* __restrict__ b3,
    const float* __restrict__ bs, const float* __restrict__ bt,
    const int* __restrict__ idxa, const int* __restrict__ idxb,
    float* __restrict__ out)
{
    using namespace cfg;
    // Disjoint LDS buffers — no unions, no aliasing. Total 56320 B.
    __shared__ __align__(16) char smem[56320];
    float*  z_s  = (float*)(smem);             // [32][40] f32      @0      (5120 B)
    bf16_t* h0   = (bf16_t*)(smem + 5120);     // [32][288] bf16    @5120   (18432 B)
    bf16_t* hA   = (bf16_t*)(smem + 23552);    // [32][136] bf16    @23552  (8704 B)
    bf16_t* hB   = (bf16_t*)(smem + 32256);    // [32][136] bf16    @32256  (8704 B)
    float*  st_s = (float*)(smem + 40960);     // [32][40] f32      @40960  (5120 B)
    bf16_t* wbuf = (bf16_t*)(smem + 46080);    // [128][40] bf16    @46080  (10240 B)

    const int tid  = threadIdx.x;
    const int lane = tid & 63;
    const int w    = tid >> 6;
    const int q    = lane >> 4, c = lane & 15;
    const int wm   = w >> 1, wn = w & 1;
    const int r0   = wm * 16, c0 = wn * 64;
    const int row0 = blockIdx.x * MB;

    // Zero-fill ALL LDS (insurance: any residual read-before-write is finite).
    {
        int4 zz = {0, 0, 0, 0};
        for (int ch = tid; ch < 56320 / 16; ch += NTH) ((int4*)smem)[ch] = zz;
    }
    __syncthreads();

    // init z from x (fp32)
    for (int e = tid; e < MB * DIM; e += NTH)
        z_s[e] = x[(size_t)row0 * DIM + e];
    float ld = 0.f;
    __syncthreads();

    for (int i = 0; i < L; ++i) {
        const int* ga = g_gtab + i * AD;
        const int* gb = g_gtab + 120 + i * AD;

        // ---- build h0[32][288] (bf16): [gathered z_a | zeros | ctx | t_e]
        for (int e = tid; e < MB * 32; e += NTH) {
            int r = e >> 5, k = e & 31;
            float v = (k < AD) ? z_s[r * DIM + ga[k]] : 0.f;
            h0[r * 288 + k] = (bf16_t)v;
        }
        for (int e2 = tid; e2 < MB * 32 * 2; e2 += NTH) {
            int t2 = e2 >> 10;           // 0: ctx, 1: te
            int e3 = e2 & 1023;
            int r = e3 >> 5, j = e3 & 31;   // j-th float4 of row r
            const float* src = t2 ? te : ctx;
            float4 v = *(const float4*)&src[(size_t)(row0 + r) * H + j * 4];
            bf16x4 bv;
            bv[0] = (bf16_t)v.x; bv[1] = (bf16_t)v.y;
            bv[2] = (bf16_t)v.z; bv[3] = (bf16_t)v.w;
            *(bf16x4*)&h0[r * 288 + 32 + t2 * 128 + j * 4] = bv;
        }
        // (mm_block's leading+post-stage barriers order h0 writes before reads)

        // ---- mm1: h0 @ W1t -> hA ; mm2: hA @ W2t -> hB ; mm3: hB @ W3t -> hA
        mm_block(h0, 288, 9, g_wsb + i * W1S_LSTR,           b1 + i * H, hA, wbuf, tid, q, c, r0, c0);
        mm_block(hA, 136, 4, g_wsb + W2S_OFF + i * W23_LSTR, b2 + i * H, hB, wbuf, tid, q, c, r0, c0);
        mm_block(hB, 136, 4, g_wsb + W3S_OFF + i * W23_LSTR, b3 + i * H, hA, wbuf, tid, q, c, r0, c0);

        // ---- st: hA @ [Ws|Wt] -> st_s (fp32; s at col j, t at col 20+j)
        {
            const bf16_t* wstl = g_wsb + WST_OFF + i * WST_LSTR;
            f32x4 acc[2] = {};
            for (int kt = 0; kt < 4; ++kt) {
                __syncthreads();
                stage_w(wstl + kt * WST_TILE, wbuf, WST_TILE * 2, tid);
                __syncthreads();
                bf16x8 af = *(const bf16x8*)&hA[(r0 + c) * 136 + kt * 32 + q * 8];
                #pragma unroll
                for (int nt = 0; nt < 2; ++nt) {
                    int n = wn * 32 + nt * 16 + c;
                    bf16x8 bfr = *(const bf16x8*)&wbuf[n * 40 + q * 8];
                    acc[nt] = MFMA16(af, bfr, acc[nt]);
                }
            }
            #pragma unroll
            for (int nt = 0; nt < 2; ++nt) {
                int n = wn * 32 + nt * 16 + c;
                bool is_s = (n < 20), is_t = (n >= 32 && n < 52);
                if (is_s || is_t) {
                    float bv = is_s ? bs[i * AD + n] : bt[i * AD + (n - 32)];
                    int col = is_s ? n : 20 + (n - 32);
                    #pragma unroll
                    for (int rr = 0; rr < 4; ++rr)
                        st_s[(r0 + q * 4 + rr) * 40 + col] = acc[nt][rr] + bv;
                }
            }
        }
        __syncthreads();   // st_s complete

        // ---- per-row epilogue: clip, exp, affine, scatter, logdet (1 thread/row)
        if (tid < MB) {
            int r = tid;
            float yv[cfg::AD], zav[cfg::AD];
            float lsum = 0.f;
            #pragma unroll
            for (int j = 0; j < AD; ++j) {
                float s = st_s[r * 40 + j];
                s = fminf(fmaxf(s, -2.f), 2.f);
                float tt = st_s[r * 40 + 20 + j];
                float zb = z_s[r * DIM + gb[j]];
                yv[j]  = zb * __expf(s) + tt;
                zav[j] = z_s[r * DIM + ga[j]];
                lsum  += s;
            }
            #pragma unroll
            for (int j = 0; j < AD; ++j) {
                z_s[r * DIM + idxa[i * AD + j]] = zav[j];
                z_s[r * DIM + idxb[i * AD + j]] = yv[j];
            }
            ld += lsum;
        }
        __syncthreads();   // z_s stable for next layer's h0 build / final write
    }

    // output: z (B x 40) then logdet (B), fp32
    for (int e = tid; e < MB * DIM; e += NTH)
        out[(size_t)row0 * DIM + e] = z_s[e];
    if (tid < MB)
        out[(size_t)B * DIM + row0 + tid] = ld;
}

extern "C" void kernel_launch(void* const* d_in, const int* in_sizes, int n_in,
                              void* d_out, int out_size, void* d_ws, size_t ws_size,
                              hipStream_t stream) {
    using namespace cfg;
    const float* x   = (const float*)d_in[0];
    const float* ctx = (const float*)d_in[1];
    const float* te  = (const float*)d_in[2];
    const float* W1  = (const float*)d_in[3];
    const float* b1  = (const float*)d_in[4];
    const float* W2  = (const float*)d_in[5];
    const float* b2  = (const float*)d_in[6];
    const float* W3  = (const float*)d_in[7];
    const float* b3  = (const float*)d_in[8];
    const float* Ws_ = (const float*)d_in[9];
    const float* bs_ = (const float*)d_in[10];
    const float* Wt_ = (const float*)d_in[11];
    const float* bt_ = (const float*)d_in[12];
    const int* perm  = (const int*)d_in[13];
    const int* ia    = (const int*)d_in[14];
    const int* ib    = (const int*)d_in[15];

    float* out = (float*)d_out;

    int total = WS_BF16_TOTAL + 240;
    prep_kernel<<<(total + 255) / 256, 256, 0, stream>>>(W1, W2, W3, Ws_, Wt_, perm, ia, ib);
    flow_main<<<B / MB, NTH, 0, stream>>>(x, ctx, te, b1, b2, b3, bs_, bt_, ia, ib, out);
}

// Round 5
// 697.131 us; speedup vs baseline: 1.9930x; 1.9930x over previous
//
#include <hip/hip_runtime.h>
#include <hip/hip_bf16.h>
#include <stdint.h>
#include <stddef.h>

typedef __bf16 bf16_t;
typedef __bf16 bf16x8 __attribute__((ext_vector_type(8)));
typedef __bf16 bf16x4 __attribute__((ext_vector_type(4)));
typedef float  f32x4  __attribute__((ext_vector_type(4)));

#define MFMA16(a, b, c) __builtin_amdgcn_mfma_f32_16x16x32_bf16((a), (b), (c), 0, 0, 0)

namespace cfg {
constexpr int B    = 131072;
constexpr int DIM  = 40;
constexpr int H    = 128;
constexpr int AD   = 20;
constexpr int L    = 6;
constexpr int MB   = 64;     // rows per block
constexpr int NTH  = 256;    // threads per block (4 waves)

// uniform transposed-weight tiles: [L][21][128][40] bf16
//   tiles 0..8  = W1 K-tiles (K padded 288)
//   tiles 9..12 = W2, 13..16 = W3, 17..20 = [Ws|Wt] (cols 0..19 s, 32..51 t)
constexpr int TILE = 128 * 40;      // 5120 elems / 10240 B
constexpr int LSTR = 21 * TILE;     // per-layer stride
constexpr int WTOT = 6 * LSTR;      // 645120 elems
}

// Static module-scope staging; rewritten by prep kernels every launch.
__device__ bf16_t g_wsb[cfg::WTOT];
__device__ int    g_gtab[240];
__device__ bf16_t g_cte[(size_t)cfg::B * 256];   // [B][ctx(128)|te(128)] bf16

// ---------------------------------------------------------------------------
// prep_w: fp32 weights -> bf16 transposed/padded tiles + gather tables
// ---------------------------------------------------------------------------
__global__ void prep_w(const float* __restrict__ W1, const float* __restrict__ W2,
                       const float* __restrict__ W3, const float* __restrict__ Ws,
                       const float* __restrict__ Wt, const int* __restrict__ perm,
                       const int* __restrict__ ia, const int* __restrict__ ib)
{
    using namespace cfg;
    int t = blockIdx.x * blockDim.x + threadIdx.x;
    if (t < WTOT) {
        int i = t / LSTR, r = t % LSTR;
        int tile = r / TILE, r2 = r % TILE;
        int n = r2 / 40, kl = r2 % 40;
        float v = 0.f;
        if (kl < 32) {
            if (tile < 9) {                      // W1: h0 k-layout [za(20) pad12 | ctx | te]
                int k = tile * 32 + kl;
                if (k < 20)       v = W1[(i * 276 + k) * 128 + n];
                else if (k >= 32) v = W1[(i * 276 + (k - 12)) * 128 + n];
            } else if (tile < 13) {
                int k = (tile - 9) * 32 + kl;
                v = W2[(i * 128 + k) * 128 + n];
            } else if (tile < 17) {
                int k = (tile - 13) * 32 + kl;
                v = W3[(i * 128 + k) * 128 + n];
            } else {
                int k = (tile - 17) * 32 + kl;
                if (n < 20)                 v = Ws[(i * 128 + k) * 20 + n];
                else if (n >= 32 && n < 52) v = Wt[(i * 128 + k) * 20 + (n - 32)];
            }
        }
        g_wsb[t] = (bf16_t)v;
    } else if (t < WTOT + 240) {
        int u = t - WTOT;
        if (u < 120) g_gtab[u] = perm[(u / 20) * 40 + ia[u]];
        else { int v2 = u - 120; g_gtab[u] = perm[(v2 / 20) * 40 + ib[v2]]; }
    }
}

// ---------------------------------------------------------------------------
// prep_cte: fp32 ctx/te -> bf16 [B][256] concat (mm1 A-operand, k-major)
// ---------------------------------------------------------------------------
__global__ void prep_cte(const float* __restrict__ ctx, const float* __restrict__ te)
{
    using namespace cfg;
    size_t t = (size_t)blockIdx.x * blockDim.x + threadIdx.x;   // one float4 each
    size_t e = t * 4;
    size_t row = e >> 8;
    int j = (int)(e & 255);
    const float* src = (j < 128) ? &ctx[row * 128 + j] : &te[row * 128 + (j - 128)];
    float4 v = *(const float4*)src;
    bf16x4 bv;
    bv[0] = (bf16_t)v.x; bv[1] = (bf16_t)v.y; bv[2] = (bf16_t)v.z; bv[3] = (bf16_t)v.w;
    *(bf16x4*)&g_cte[row * 256 + j] = bv;
}

// [64 x 128] @ [128 x 128] + bias -> SiLU -> hout[64][136].
// A from LDS; B-frags DIRECT from global (L1-resident) — no barriers inside.
__device__ __forceinline__ void mm_dense(
    const bf16_t* hin, const bf16_t* __restrict__ wl, const float* __restrict__ bias,
    bf16_t* hout, int q, int c, int r0, int c0)
{
    using namespace cfg;
    f32x4 acc[2][4] = {};
    #pragma unroll
    for (int kt = 0; kt < 4; ++kt) {
        bf16x8 af0 = *(const bf16x8*)&hin[(r0 + c) * 136 + kt * 32 + q * 8];
        bf16x8 af1 = *(const bf16x8*)&hin[(r0 + 16 + c) * 136 + kt * 32 + q * 8];
        #pragma unroll
        for (int nt = 0; nt < 4; ++nt) {
            bf16x8 bfr = *(const bf16x8*)&wl[kt * TILE + (c0 + nt * 16 + c) * 40 + q * 8];
            acc[0][nt] = MFMA16(af0, bfr, acc[0][nt]);
            acc[1][nt] = MFMA16(af1, bfr, acc[1][nt]);
        }
    }
    #pragma unroll
    for (int nt = 0; nt < 4; ++nt) {
        int col = c0 + nt * 16 + c;
        float bv = bias[col];
        #pragma unroll
        for (int mt = 0; mt < 2; ++mt)
            #pragma unroll
            for (int rr = 0; rr < 4; ++rr) {
                float v = acc[mt][nt][rr] + bv;
                v = v / (1.f + __expf(-v));
                hout[(r0 + mt * 16 + q * 4 + rr) * 136 + col] = (bf16_t)v;
            }
    }
}

__global__ __launch_bounds__(256, 3) void flow_main(
    const float* __restrict__ x,
    const float* __restrict__ b1, const float* __restrict__ b2, const float* __restrict__ b3,
    const float* __restrict__ bs, const float* __restrict__ bt,
    const int* __restrict__ idxa, const int* __restrict__ idxb,
    float* __restrict__ out)
{
    using namespace cfg;
    // LDS: 50176 B -> 3 blocks/CU. st_s aliases hB (disjoint lifetimes, barrier-fenced).
    __shared__ __align__(16) char smem[50176];
    float*  z_s  = (float*)(smem);             // [64][40] f32   @0      (10240 B)
    bf16_t* za   = (bf16_t*)(smem + 10240);    // [64][40] bf16  @10240  (5120 B; cols 0..31 used)
    bf16_t* hA   = (bf16_t*)(smem + 15360);    // [64][136] bf16 @15360  (17408 B)
    bf16_t* hB   = (bf16_t*)(smem + 32768);    // [64][136] bf16 @32768  (17408 B)
    float*  st_s = (float*)(smem + 32768);     // [64][40] f32 — ALIASES hB (dead then)

    const int tid  = threadIdx.x;
    const int lane = tid & 63;
    const int w    = tid >> 6;
    const int q    = lane >> 4, c = lane & 15;
    const int wm   = w >> 1, wn = w & 1;
    const int r0   = wm * 32, c0 = wn * 64;
    const int row0 = blockIdx.x * MB;

    // Zero-fill LDS once (insurance: residual read-before-write is finite).
    {
        int4 zz = {0, 0, 0, 0};
        for (int ch = tid; ch < 50176 / 16; ch += NTH) ((int4*)smem)[ch] = zz;
    }
    __syncthreads();

    for (int e = tid; e < MB * DIM; e += NTH)
        z_s[e] = x[(size_t)row0 * DIM + e];
    float ld = 0.f;
    __syncthreads();

    for (int i = 0; i < L; ++i) {
        const int* ga = g_gtab + i * AD;
        const int* gb = g_gtab + 120 + i * AD;
        const bf16_t* wlay = g_wsb + i * LSTR;

        // ---- za[64][40]: gathered z_a (cols 0..19 real, 20..31 zero)
        for (int e = tid; e < MB * 32; e += NTH) {
            int r = e >> 5, k = e & 31;
            float v = (k < AD) ? z_s[r * DIM + ga[k]] : 0.f;
            za[r * 40 + k] = (bf16_t)v;
        }
        __syncthreads();                       // za ready (also z_s stable)

        // ---- mm1: [za | cte] @ W1t -> hA. kt=0 from za LDS; kt=1..8 from g_cte global.
        {
            f32x4 acc[2][4] = {};
            {   // K-tile 0 (z_a)
                bf16x8 af0 = *(const bf16x8*)&za[(r0 + c) * 40 + q * 8];
                bf16x8 af1 = *(const bf16x8*)&za[(r0 + 16 + c) * 40 + q * 8];
                #pragma unroll
                for (int nt = 0; nt < 4; ++nt) {
                    bf16x8 bfr = *(const bf16x8*)&wlay[(c0 + nt * 16 + c) * 40 + q * 8];
                    acc[0][nt] = MFMA16(af0, bfr, acc[0][nt]);
                    acc[1][nt] = MFMA16(af1, bfr, acc[1][nt]);
                }
            }
            #pragma unroll
            for (int kt = 1; kt < 9; ++kt) {   // ctx/te from global bf16 (L1-hot)
                bf16x8 af0 = *(const bf16x8*)&g_cte[(size_t)(row0 + r0 + c) * 256 + (kt - 1) * 32 + q * 8];
                bf16x8 af1 = *(const bf16x8*)&g_cte[(size_t)(row0 + r0 + 16 + c) * 256 + (kt - 1) * 32 + q * 8];
                #pragma unroll
                for (int nt = 0; nt < 4; ++nt) {
                    bf16x8 bfr = *(const bf16x8*)&wlay[kt * TILE + (c0 + nt * 16 + c) * 40 + q * 8];
                    acc[0][nt] = MFMA16(af0, bfr, acc[0][nt]);
                    acc[1][nt] = MFMA16(af1, bfr, acc[1][nt]);
                }
            }
            #pragma unroll
            for (int nt = 0; nt < 4; ++nt) {
                int col = c0 + nt * 16 + c;
                float bv = b1[i * H + col];
                #pragma unroll
                for (int mt = 0; mt < 2; ++mt)
                    #pragma unroll
                    for (int rr = 0; rr < 4; ++rr) {
                        float v = acc[mt][nt][rr] + bv;
                        v = v / (1.f + __expf(-v));
                        hA[(r0 + mt * 16 + q * 4 + rr) * 136 + col] = (bf16_t)v;
                    }
            }
        }
        __syncthreads();                       // hA ready

        mm_dense(hA, wlay + 9 * TILE,  b2 + i * H, hB, q, c, r0, c0);
        __syncthreads();                       // hB ready
        mm_dense(hB, wlay + 13 * TILE, b3 + i * H, hA, q, c, r0, c0);
        __syncthreads();                       // hA(h3) ready; hB dead -> st_s

        // ---- st: hA @ [Ws|Wt] -> st_s fp32 (s at col j, t at col 20+j)
        {
            const bf16_t* wst = wlay + 17 * TILE;
            f32x4 acc[2][2] = {};
            #pragma unroll
            for (int kt = 0; kt < 4; ++kt) {
                bf16x8 af0 = *(const bf16x8*)&hA[(r0 + c) * 136 + kt * 32 + q * 8];
                bf16x8 af1 = *(const bf16x8*)&hA[(r0 + 16 + c) * 136 + kt * 32 + q * 8];
                #pragma unroll
                for (int nt = 0; nt < 2; ++nt) {
                    int n = wn * 32 + nt * 16 + c;
                    bf16x8 bfr = *(const bf16x8*)&wst[kt * TILE + n * 40 + q * 8];
                    acc[0][nt] = MFMA16(af0, bfr, acc[0][nt]);
                    acc[1][nt] = MFMA16(af1, bfr, acc[1][nt]);
                }
            }
            #pragma unroll
            for (int nt = 0; nt < 2; ++nt) {
                int n = wn * 32 + nt * 16 + c;
                bool is_s = (n < 20), is_t = (n >= 32 && n < 52);
                if (is_s || is_t) {
                    float bv = is_s ? bs[i * AD + n] : bt[i * AD + (n - 32)];
                    int col = is_s ? n : 20 + (n - 32);
                    #pragma unroll
                    for (int mt = 0; mt < 2; ++mt)
                        #pragma unroll
                        for (int rr = 0; rr < 4; ++rr)
                            st_s[(r0 + mt * 16 + q * 4 + rr) * 40 + col] = acc[mt][nt][rr] + bv;
                }
            }
        }
        __syncthreads();                       // st_s complete

        // ---- per-row epilogue (1 thread/row): clip, exp, affine, scatter, logdet
        if (tid < MB) {
            int r = tid;
            float yv[cfg::AD], zav[cfg::AD];
            float lsum = 0.f;
            #pragma unroll
            for (int j = 0; j < AD; ++j) {
                float s = st_s[r * 40 + j];
                s = fminf(fmaxf(s, -2.f), 2.f);
                float tt = st_s[r * 40 + 20 + j];
                float zb = z_s[r * DIM + gb[j]];
                yv[j]  = zb * __expf(s) + tt;
                zav[j] = z_s[r * DIM + ga[j]];
                lsum  += s;
            }
            #pragma unroll
            for (int j = 0; j < AD; ++j) {
                z_s[r * DIM + idxa[i * AD + j]] = zav[j];
                z_s[r * DIM + idxb[i * AD + j]] = yv[j];
            }
            ld += lsum;
        }
        __syncthreads();                       // z_s stable for next layer
    }

    for (int e = tid; e < MB * DIM; e += NTH)
        out[(size_t)row0 * DIM + e] = z_s[e];
    if (tid < MB)
        out[(size_t)B * DIM + row0 + tid] = ld;
}

extern "C" void kernel_launch(void* const* d_in, const int* in_sizes, int n_in,
                              void* d_out, int out_size, void* d_ws, size_t ws_size,
                              hipStream_t stream) {
    using namespace cfg;
    const float* x   = (const float*)d_in[0];
    const float* ctx = (const float*)d_in[1];
    const float* te  = (const float*)d_in[2];
    const float* W1  = (const float*)d_in[3];
    const float* b1  = (const float*)d_in[4];
    const float* W2  = (const float*)d_in[5];
    const float* b2  = (const float*)d_in[6];
    const float* W3  = (const float*)d_in[7];
    const float* b3  = (const float*)d_in[8];
    const float* Ws_ = (const float*)d_in[9];
    const float* bs_ = (const float*)d_in[10];
    const float* Wt_ = (const float*)d_in[11];
    const float* bt_ = (const float*)d_in[12];
    const int* perm  = (const int*)d_in[13];
    const int* ia    = (const int*)d_in[14];
    const int* ib    = (const int*)d_in[15];

    float* out = (float*)d_out;

    int totw = WTOT + 240;
    prep_w<<<(totw + 255) / 256, 256, 0, stream>>>(W1, W2, W3, Ws_, Wt_, perm, ia, ib);
    prep_cte<<<((size_t)B * 256 / 4) / 256, 256, 0, stream>>>(ctx, te);
    flow_main<<<B / MB, NTH, 0, stream>>>(x, b1, b2, b3, bs_, bt_, ia, ib, out);
}